// Round 1
// 2331.135 us; speedup vs baseline: 3.9351x; 3.9351x over previous
//
#include <hip/hip_runtime.h>
#include <hip/hip_bf16.h>

typedef __hip_bfloat16 bf16;
typedef __attribute__((ext_vector_type(4))) float  f32x4;
typedef __attribute__((ext_vector_type(8))) short  s16x8;

#define B_   32
#define CIN  1024
#define COUT 512
#define NSP  1568   // T*H*W = 8*14*14
#define NH   8
#define DK   64

#define PROJ_ELEMS ((size_t)B_ * COUT * NSP)                     // 25,690,112
#define X_ELEMS    ((size_t)B_ * CIN  * NSP)                     // 51,380,224
#define ATTN_BYTES ((size_t)B_ * NH * DK * DK * sizeof(float))   // 4 MB

// ---------- runtime dtype detection (unchanged from previous session) ----------
__device__ __forceinline__ bool inputs_are_f32(const void* det) {
    const unsigned short* u = (const unsigned short*)det;
    unsigned big = 0;
    for (int t = 0; t < 256; ++t) {
        unsigned e = (u[t] >> 7) & 0xFF;
        big |= (e >= 160) ? 1u : 0u;
    }
    return big != 0;
}

// ---------- typed load/store ----------
template<typename T> struct VT;
template<> struct VT<bf16> {
    static __device__ __forceinline__ float ld(const bf16* p) {
        return __uint_as_float(((unsigned)*(const unsigned short*)p) << 16);
    }
    static __device__ __forceinline__ void st(bf16* p, float v) {
        *p = __float2bfloat16(v);
    }
};
template<> struct VT<float> {
    static __device__ __forceinline__ float ld(const float* p) { return *p; }
    static __device__ __forceinline__ void st(float* p, float v) { *p = v; }
};

// ---------- legacy (bf16-input path) scratch resolution ----------
template<typename T>
__device__ __forceinline__ char* scratch_base(void* ws, unsigned long long ws_size,
                                              void* qbuf) {
    unsigned long long need =
        (unsigned long long)ATTN_BYTES + (unsigned long long)(PROJ_ELEMS * sizeof(T));
    return (ws_size >= need) ? (char*)ws : (char*)qbuf;
}

// ============================================================================
// LEGACY VALU pipeline — retained for bf16 inputs only (f32 path now uses MFMA).
// ============================================================================
template<typename T>
__device__ void proj_impl(const T* __restrict__ X, const T* __restrict__ W,
                          const T* __restrict__ bias, T* __restrict__ P,
                          int Cin, int Cout, int N, float* Ws)
{
    const int tid = threadIdx.x;
    const int o0 = blockIdx.y * 4;
    const int b  = blockIdx.z;

    for (int e = tid; e < Cin * 4; e += 256) {
        int ro = e & 3, c = e >> 2;
        Ws[c * 4 + ro] = VT<T>::ld(W + (size_t)(o0 + ro) * Cin + c);
    }
    __syncthreads();

    int n0 = blockIdx.x * 512 + tid * 2;
    if (n0 >= N) return;

    const T* Xb = X + (size_t)b * Cin * N + n0;

    float a00, a01, a10, a11, a20, a21, a30, a31;
    a00 = a01 = VT<T>::ld(bias + o0 + 0);
    a10 = a11 = VT<T>::ld(bias + o0 + 1);
    a20 = a21 = VT<T>::ld(bias + o0 + 2);
    a30 = a31 = VT<T>::ld(bias + o0 + 3);

    for (int c = 0; c < Cin; ++c) {
        float x0 = VT<T>::ld(Xb + (size_t)c * N);
        float x1 = VT<T>::ld(Xb + (size_t)c * N + 1);
        float w0 = Ws[c * 4 + 0], w1 = Ws[c * 4 + 1];
        float w2 = Ws[c * 4 + 2], w3 = Ws[c * 4 + 3];
        a00 += x0 * w0; a01 += x1 * w0;
        a10 += x0 * w1; a11 += x1 * w1;
        a20 += x0 * w2; a21 += x1 * w2;
        a30 += x0 * w3; a31 += x1 * w3;
    }
    {
        size_t base = ((size_t)b * Cout + o0) * N + n0;
        VT<T>::st(P + base + 0 * (size_t)N, a00); VT<T>::st(P + base + 0 * (size_t)N + 1, a01);
        VT<T>::st(P + base + 1 * (size_t)N, a10); VT<T>::st(P + base + 1 * (size_t)N + 1, a11);
        VT<T>::st(P + base + 2 * (size_t)N, a20); VT<T>::st(P + base + 2 * (size_t)N + 1, a21);
        VT<T>::st(P + base + 3 * (size_t)N, a30); VT<T>::st(P + base + 3 * (size_t)N + 1, a31);
    }
}

__global__ __launch_bounds__(256) void proj_g(
    const void* Xin, int x_is_scratch,
    void* ws, unsigned long long ws_size, void* qbuf,
    const void* W, const void* bias,
    void* Pbase, unsigned long long p_off,
    int Cin, int Cout, int N, const void* det)
{
    if (inputs_are_f32(det)) return;   // f32 handled by the MFMA pipeline
    __shared__ float Ws[4096];
    const bf16* X = x_is_scratch
        ? (const bf16*)(scratch_base<bf16>(ws, ws_size, qbuf) + ATTN_BYTES)
        : (const bf16*)Xin;
    proj_impl<bf16>(X, (const bf16*)W, (const bf16*)bias,
                    (bf16*)Pbase + p_off, Cin, Cout, N, Ws);
}

// ---------- attn: softmax_j over (K^T Q)/8, per (b, head) ----------
template<typename T>
__device__ void attn_impl(const T* __restrict__ K, const T* __restrict__ Q,
                          float* __restrict__ attnW, int N, float* smem)
{
    float* Ks = smem;            // [32][64]
    float* Qs = smem + 2048;     // [32][64]
    float* Sa = smem + 4096;     // [64][65]
    const int tid = threadIdx.x;
    const int hh = blockIdx.x, b = blockIdx.y;

    const T* Kb = K + (size_t)b * COUT * N + hh * DK;
    const T* Qb = Q + (size_t)b * COUT * N + hh * DK;

    const int ti = tid & 15;
    const int tj = tid >> 4;
    float acc[4][4] = {};

    for (int c0 = 0; c0 < N; c0 += 32) {
        __syncthreads();
        for (int e = tid; e < 2048; e += 256) {
            int i = e & 63, nn = e >> 6;
            size_t g = (size_t)(c0 + nn) * COUT + i;
            Ks[nn * 64 + i] = VT<T>::ld(Kb + g);
            Qs[nn * 64 + i] = VT<T>::ld(Qb + g);
        }
        __syncthreads();
        for (int nn = 0; nn < 32; ++nn) {
            float kv[4], qv[4];
#pragma unroll
            for (int t = 0; t < 4; ++t) {
                kv[t] = Ks[nn * 64 + ti * 4 + t];
                qv[t] = Qs[nn * 64 + tj * 4 + t];
            }
#pragma unroll
            for (int ii = 0; ii < 4; ++ii)
#pragma unroll
                for (int jj = 0; jj < 4; ++jj)
                    acc[ii][jj] += kv[ii] * qv[jj];
        }
    }

    __syncthreads();
#pragma unroll
    for (int ii = 0; ii < 4; ++ii)
#pragma unroll
        for (int jj = 0; jj < 4; ++jj)
            Sa[(ti * 4 + ii) * 65 + tj * 4 + jj] = acc[ii][jj] * 0.125f;
    __syncthreads();

    if (tid < 64) {
        int r = tid;
        float m = -1e30f;
        for (int j = 0; j < 64; ++j) m = fmaxf(m, Sa[r * 65 + j]);
        float s = 0.f;
        for (int j = 0; j < 64; ++j) s += expf(Sa[r * 65 + j] - m);
        float inv = 1.f / s;
        float* outp = attnW + (((size_t)b * NH + hh) * DK + r) * DK;
        for (int j = 0; j < 64; ++j) outp[j] = expf(Sa[r * 65 + j] - m) * inv;
    }
}

__global__ __launch_bounds__(256) void attn_g(
    const void* KQbase, unsigned long long k_off, unsigned long long q_off,
    void* ws, unsigned long long ws_size, void* qbuf, int N, const void* det)
{
    if (inputs_are_f32(det)) return;
    __shared__ float smem[2048 + 2048 + 64 * 65];
    float* attnW = (float*)scratch_base<bf16>(ws, ws_size, qbuf);
    attn_impl<bf16>((const bf16*)KQbase + k_off, (const bf16*)KQbase + q_off,
                    attnW, N, smem);
}

// ---------- av: out3[b, i*8+hh, n] = sum_j attn[b,hh,i,j] * V[b, n*512+hh*64+j] ----------
template<typename T>
__device__ void av_impl(const float* __restrict__ attnW, const T* __restrict__ V,
                        T* __restrict__ out3, int N, float* smem)
{
    float* As = smem;          // [64][64]
    float* Vs = smem + 4096;   // [64][65]
    const int tid = threadIdx.x;
    const int nt = blockIdx.x, hh = blockIdx.y, b = blockIdx.z;

    const float* Ab = attnW + ((size_t)(b * NH + hh)) * (DK * DK);
    for (int e = tid; e < 4096; e += 256) As[e] = Ab[e];

    const T* Vb = V + (size_t)b * COUT * N + hh * DK;
    for (int e = tid; e < 4096; e += 256) {
        int j = e & 63, nn = e >> 6;
        int n = nt * 64 + nn;
        Vs[nn * 65 + j] = (n < N) ? VT<T>::ld(Vb + (size_t)n * COUT + j) : 0.f;
    }
    __syncthreads();

    const int nl = tid & 63;
    const int ig = tid >> 6;
    const int n = nt * 64 + nl;

    float acc[16] = {};
    for (int j = 0; j < 64; ++j) {
        float v = Vs[nl * 65 + j];
#pragma unroll
        for (int k = 0; k < 16; ++k)
            acc[k] += As[(ig * 16 + k) * 64 + j] * v;
    }

    if (n < N) {
#pragma unroll
        for (int k = 0; k < 16; ++k) {
            int i = ig * 16 + k;
            int o = i * 8 + hh;
            VT<T>::st(out3 + ((size_t)b * COUT + o) * N + n, acc[k]);
        }
    }
}

__global__ __launch_bounds__(256) void av_g(
    void* ws, unsigned long long ws_size, void* qbuf,
    const void* Vbase, unsigned long long v_off, int N, const void* det)
{
    if (inputs_are_f32(det)) return;
    __shared__ float smem[4096 + 64 * 65];
    char* sb = scratch_base<bf16>(ws, ws_size, qbuf);
    av_impl<bf16>((const float*)sb, (const bf16*)Vbase + v_off,
                  (bf16*)(sb + ATTN_BYTES), N, smem);
}

// ============================================================================
// NEW f32 MFMA pipeline.
//
// Buffer plan (f32 path; E = X_ELEMS shorts, P = PROJ_ELEMS; qb=query buf, do=d_out):
//  1. prep_q : query          -> Qt_h @do[0:E*2), Qt_l @do[E*2:E*4)
//  2. gemm<3>: Qt (+query_w)  -> Q_lin f32 @qb[0:P*4)
//  3. prep_x : x              -> Xt_h @do[0:E*2), Xt_l @do[E*2:E*4)   (Qt dead)
//  4. gemm<3>: Xt (+key_w)    -> K_lin f32 @qb[P*4:P*8)
//  5. gemm<1>: Xt_h (+val_w)  -> V_lin f32 @do[E*2:E*4)               (Xt_l dead)
//  6. attn   : K,Q            -> attnW f32 @do[0:4MB)                 (Xt_h dead)
//  7. av     : attnW,V        -> out3 f32 @qb[0:P*4)                  (Q/K_lin dead)
//  8. prep_o : out3           -> O3t_h @qb[P*4:P*6), O3t_l @qb[P*6:P*8)
//  9. gemm<3>: O3t (+up_w)    -> final f32 @do[0:E*4)                 (attnW,V dead)
// ============================================================================

__device__ __forceinline__ void split_bf16(float v, unsigned short& h, unsigned short& l,
                                           float& hf) {
    bf16 hb = __float2bfloat16(v);
    h  = *(unsigned short*)&hb;
    hf = __bfloat162float(hb);
    bf16 lb = __float2bfloat16(v - hf);
    l  = *(unsigned short*)&lb;
}

// ---------- transpose + hi/lo split: src[b][C][NSP] f32 -> h/l [b][NSP][C] bf16 ----------
__global__ __launch_bounds__(256) void prep_g(
    const float* __restrict__ src, short* __restrict__ h, short* __restrict__ l,
    int C, const void* det)
{
    if (!inputs_are_f32(det)) return;
    __shared__ float tile[64][65];
    const int tid = threadIdx.x;
    const int n0 = blockIdx.x * 64, c0 = blockIdx.y * 64, b = blockIdx.z;

    {   // read: lanes sweep n (coalesced), 4 c-rows per pass
        const int tn = tid & 63, tc = tid >> 6;
        int n = n0 + tn; if (n >= NSP) n = NSP - 1;
        const float* s = src + ((size_t)b * C + c0) * NSP + n;
#pragma unroll
        for (int p = 0; p < 16; ++p) {
            int cl = p * 4 + tc;
            tile[cl][tn] = s[(size_t)cl * NSP];
        }
    }
    __syncthreads();
    {   // write: lanes sweep c (2 each, packed u32), coalesced
        const int tc = (tid & 31) * 2, tn8 = tid >> 5;
#pragma unroll
        for (int p = 0; p < 8; ++p) {
            int nl = p * 8 + tn8;
            int n = n0 + nl;
            if (n < NSP) {
                float v0 = tile[tc][nl], v1 = tile[tc + 1][nl];
                unsigned short h0, l0, h1, l1; float f0, f1;
                split_bf16(v0, h0, l0, f0);
                split_bf16(v1, h1, l1, f1);
                size_t base = ((size_t)b * NSP + n) * C + c0 + tc;
                *(unsigned*)(h + base) = (unsigned)h0 | ((unsigned)h1 << 16);
                *(unsigned*)(l + base) = (unsigned)l0 | ((unsigned)l1 << 16);
            }
        }
    }
}

// ---------- MFMA GEMM: C[b][o][n] = sum_k A[o][k]*Bt[b][n][k] + bias[o] ----------
// A: f32 [M][K] (weights, hi/lo split on the fly into LDS)
// Bt: bf16 hi(/lo) [b][NSP][K] from prep_g
// NT=3: bf16x3 (Ah*Bh + Ah*Bl + Al*Bh). NT=1: Ah*Bh only.
// Tiles: BM=128, BN=128, BK=64. 4 waves, 64x64 per wave, 16x16x32 MFMA.
// LDS rows are 128B, XOR-swizzled chunk^=(row&7) for conflict-free ds_read_b128;
// B staged with global_load_lds(16B) using pre-swizzled per-lane SOURCE (linear dest).
template<int NT>
__global__ __launch_bounds__(256, 2) void gemm_g(
    const short* __restrict__ Bh, const short* __restrict__ Bl,
    const float* __restrict__ A, const float* __restrict__ bias,
    float* __restrict__ C, int M, int K, const void* det)
{
    if (!inputs_are_f32(det)) return;

    __shared__ __align__(16) short smem[(NT == 3) ? 32768 : 16384];
    short* Ah_s = smem;                                   // [128][64] swizzled
    short* Al_s = (NT == 3) ? (smem + 8192)  : nullptr;
    short* Bh_s = (NT == 3) ? (smem + 16384) : (smem + 8192);
    short* Bl_s = (NT == 3) ? (smem + 24576) : nullptr;

    const int tid  = threadIdx.x;
    const int lane = tid & 63, wid = tid >> 6;
    const int m0 = blockIdx.x * 128, n0 = blockIdx.y * 128, b = blockIdx.z;
    const size_t Bbase = (size_t)b * NSP * K;

    const int wm = wid >> 1, wn = wid & 1;     // 2x2 wave grid
    const int lm = lane & 15, g = lane >> 4;   // MFMA lane decomposition

    f32x4 acc[4][4];
#pragma unroll
    for (int i = 0; i < 4; ++i)
#pragma unroll
        for (int j = 0; j < 4; ++j)
#pragma unroll
            for (int r = 0; r < 4; ++r) acc[i][j][r] = 0.f;

    const int kq  = tid & 15;    // float4 column within BK=64
    const int ar0 = tid >> 4;    // row within 16-row pass

    for (int kt = 0; kt < K; kt += 64) {
        __syncthreads();
        // ---- stage A: f32 weights -> bf16 hi/lo, swizzled LDS ----
#pragma unroll
        for (int p = 0; p < 8; ++p) {
            int ml = p * 16 + ar0;
            f32x4 w4 = *(const f32x4*)(A + (size_t)(m0 + ml) * K + kt + kq * 4);
            unsigned short h[4], lo[4]; float hf;
#pragma unroll
            for (int u = 0; u < 4; ++u) split_bf16(w4[u], h[u], lo[u], hf);
            unsigned long long hp = (unsigned long long)h[0] |
                                    ((unsigned long long)h[1] << 16) |
                                    ((unsigned long long)h[2] << 32) |
                                    ((unsigned long long)h[3] << 48);
            int off = ml * 128 + ((((kq >> 1) ^ (ml & 7)) << 4)) + ((kq & 1) << 3);
            *(unsigned long long*)((char*)Ah_s + off) = hp;
            if (NT == 3) {
                unsigned long long lp = (unsigned long long)lo[0] |
                                        ((unsigned long long)lo[1] << 16) |
                                        ((unsigned long long)lo[2] << 32) |
                                        ((unsigned long long)lo[3] << 48);
                *(unsigned long long*)((char*)Al_s + off) = lp;
            }
        }
        // ---- stage B: global_load_lds, swizzle folded into per-lane source ----
        {
            const int c = lane & 7;
#pragma unroll
            for (int q = 0; q < 4; ++q) {
                int row = wid * 32 + q * 8 + (lane >> 3);
                int n = n0 + row; if (n >= NSP) n = NSP - 1;
                int csw = c ^ (row & 7);
                const short* gs = Bh + Bbase + (size_t)n * K + kt + csw * 8;
                __builtin_amdgcn_global_load_lds(gs, Bh_s + (size_t)(wid * 32 + q * 8) * 64,
                                                 16, 0, 0);
                if (NT == 3) {
                    const short* gl = Bl + Bbase + (size_t)n * K + kt + csw * 8;
                    __builtin_amdgcn_global_load_lds(gl, Bl_s + (size_t)(wid * 32 + q * 8) * 64,
                                                     16, 0, 0);
                }
            }
        }
        __syncthreads();   // drains vmcnt+lgkmcnt before frag reads

        // ---- compute: 2 k-substeps of 32 ----
#pragma unroll
        for (int s = 0; s < 2; ++s) {
            s16x8 a_h[4], a_l[4], b_h[4], b_l[4];
#pragma unroll
            for (int i = 0; i < 4; ++i) {
                int m = wm * 64 + i * 16 + lm;
                int off = m * 128 + (((((s << 2) + g) ^ (m & 7))) << 4);
                a_h[i] = *(const s16x8*)((const char*)Ah_s + off);
                if (NT == 3) a_l[i] = *(const s16x8*)((const char*)Al_s + off);
            }
#pragma unroll
            for (int j = 0; j < 4; ++j) {
                int n = wn * 64 + j * 16 + lm;
                int off = n * 128 + (((((s << 2) + g) ^ (n & 7))) << 4);
                b_h[j] = *(const s16x8*)((const char*)Bh_s + off);
                if (NT == 3) b_l[j] = *(const s16x8*)((const char*)Bl_s + off);
            }
#pragma unroll
            for (int i = 0; i < 4; ++i)
#pragma unroll
                for (int j = 0; j < 4; ++j) {
                    acc[i][j] = __builtin_amdgcn_mfma_f32_16x16x32_bf16(
                                    a_h[i], b_h[j], acc[i][j], 0, 0, 0);
                    if (NT == 3) {
                        acc[i][j] = __builtin_amdgcn_mfma_f32_16x16x32_bf16(
                                        a_h[i], b_l[j], acc[i][j], 0, 0, 0);
                        acc[i][j] = __builtin_amdgcn_mfma_f32_16x16x32_bf16(
                                        a_l[i], b_h[j], acc[i][j], 0, 0, 0);
                    }
                }
        }
    }

    // ---- epilogue: C/D layout col=lane&15, row=(lane>>4)*4+reg ----
    float bv[4][4];
#pragma unroll
    for (int i = 0; i < 4; ++i)
#pragma unroll
        for (int r = 0; r < 4; ++r)
            bv[i][r] = bias[m0 + wm * 64 + i * 16 + g * 4 + r];
#pragma unroll
    for (int j = 0; j < 4; ++j) {
        int n = n0 + wn * 64 + j * 16 + lm;
        if (n < NSP) {
#pragma unroll
            for (int i = 0; i < 4; ++i) {
                size_t cb = ((size_t)b * M + (m0 + wm * 64 + i * 16 + g * 4)) * NSP + n;
#pragma unroll
                for (int r = 0; r < 4; ++r)
                    C[cb + (size_t)r * NSP] = acc[i][j][r] + bv[i][r];
            }
        }
    }
}

// ---------- f32 wrappers for attn / av (reuse legacy impls) ----------
__global__ __launch_bounds__(256) void attn2_g(
    const float* __restrict__ Q, const float* __restrict__ K_,
    float* __restrict__ attnW, const void* det)
{
    if (!inputs_are_f32(det)) return;
    __shared__ float smem[2048 + 2048 + 64 * 65];
    attn_impl<float>(K_, Q, attnW, NSP, smem);
}

__global__ __launch_bounds__(256) void av2_g(
    const float* __restrict__ attnW, const float* __restrict__ V,
    float* __restrict__ out3, const void* det)
{
    if (!inputs_are_f32(det)) return;
    __shared__ float smem[4096 + 64 * 65];
    av_impl<float>(attnW, V, out3, NSP, smem);
}

// ============================================================================
extern "C" void kernel_launch(void* const* d_in, const int* in_sizes, int n_in,
                              void* d_out, int out_size, void* d_ws, size_t ws_size,
                              hipStream_t stream)
{
    const void* x   = d_in[0];
    const void* qry = d_in[1];
    const void* kw  = d_in[2];
    const void* kb  = d_in[3];
    const void* qw  = d_in[4];
    const void* qb_ = d_in[5];
    const void* vw  = d_in[6];
    const void* vb  = d_in[7];
    const void* uw  = d_in[8];
    const void* ub  = d_in[9];
    const void* det = kw;
    void* qbuf = (void*)d_in[1];
    unsigned long long wsz = (unsigned long long)ws_size;

    const int N = NSP;
    dim3 blk(256);

    // ---------------- legacy pipeline (active only for bf16 inputs) ----------------
    dim3 g1((N + 511) / 512, COUT / 4, B_);
    dim3 g2((N + 511) / 512, CIN / 4, B_);
    hipLaunchKernelGGL(proj_g, g1, blk, 0, stream, x, 0, d_ws, wsz, qbuf,
                       kw, kb, d_out, 0ull, CIN, COUT, N, det);
    hipLaunchKernelGGL(proj_g, g1, blk, 0, stream, qry, 0, d_ws, wsz, qbuf,
                       qw, qb_, d_out, (unsigned long long)PROJ_ELEMS, CIN, COUT, N, det);
    hipLaunchKernelGGL(attn_g, dim3(NH, B_), blk, 0, stream, d_out, 0ull,
                       (unsigned long long)PROJ_ELEMS, d_ws, wsz, qbuf, N, det);
    hipLaunchKernelGGL(proj_g, g1, blk, 0, stream, x, 0, d_ws, wsz, qbuf,
                       vw, vb, d_out, 0ull, CIN, COUT, N, det);
    hipLaunchKernelGGL(av_g, dim3((N + 63) / 64, NH, B_), blk, 0, stream,
                       d_ws, wsz, qbuf, d_out, 0ull, N, det);
    hipLaunchKernelGGL(proj_g, g2, blk, 0, stream, nullptr, 1, d_ws, wsz, qbuf,
                       uw, ub, d_out, 0ull, COUT, CIN, N, det);

    // ---------------- MFMA pipeline (active only for f32 inputs) ----------------
    char* dob = (char*)d_out;
    char* qb  = (char*)qbuf;

    short* Qt_h = (short*)(dob);
    short* Qt_l = (short*)(dob + X_ELEMS * 2);
    short* Xt_h = Qt_h;
    short* Xt_l = Qt_l;
    float* Qlin = (float*)(qb);
    float* Klin = (float*)(qb + PROJ_ELEMS * 4);
    float* Vlin = (float*)(dob + X_ELEMS * 2);
    float* attnW = (float*)(dob);
    float* out3  = (float*)(qb);
    short* O3t_h = (short*)(qb + PROJ_ELEMS * 4);
    short* O3t_l = (short*)(qb + PROJ_ELEMS * 6);

    dim3 gp(25, CIN / 64, B_);    // transpose 1024-chan
    dim3 gpo(25, COUT / 64, B_);  // transpose 512-chan
    dim3 gq(COUT / 128, 13, B_);  // M=512 GEMM
    dim3 gu(CIN / 128, 13, B_);   // M=1024 GEMM

    // 1. query -> Qt (hi/lo)
    hipLaunchKernelGGL(prep_g, gp, blk, 0, stream, (const float*)qry, Qt_h, Qt_l, CIN, det);
    // 2. Q projection (bf16x3) -> Q_lin
    hipLaunchKernelGGL((gemm_g<3>), gq, blk, 0, stream, (const short*)Qt_h, (const short*)Qt_l,
                       (const float*)qw, (const float*)qb_, Qlin, COUT, CIN, det);
    // 3. x -> Xt (hi/lo)  (Qt dead)
    hipLaunchKernelGGL(prep_g, gp, blk, 0, stream, (const float*)x, Xt_h, Xt_l, CIN, det);
    // 4. K projection (bf16x3) -> K_lin
    hipLaunchKernelGGL((gemm_g<3>), gq, blk, 0, stream, (const short*)Xt_h, (const short*)Xt_l,
                       (const float*)kw, (const float*)kb, Klin, COUT, CIN, det);
    // 5. V projection (hi-only) -> V_lin @ Xt_l's slot (Xt_l dead; reads only Xt_h)
    hipLaunchKernelGGL((gemm_g<1>), gq, blk, 0, stream, (const short*)Xt_h, (const short*)Xt_h,
                       (const float*)vw, (const float*)vb, Vlin, COUT, CIN, det);
    // 6. attention weights (Xt_h dead)
    hipLaunchKernelGGL(attn2_g, dim3(NH, B_), blk, 0, stream, Qlin, Klin, attnW, det);
    // 7. out3 = attn @ V  (Q_lin/K_lin dead)
    hipLaunchKernelGGL(av2_g, dim3(25, NH, B_), blk, 0, stream, attnW, Vlin, out3, det);
    // 8. out3 -> O3t (hi/lo)
    hipLaunchKernelGGL(prep_g, gpo, blk, 0, stream, out3, O3t_h, O3t_l, COUT, det);
    // 9. final projection (bf16x3) -> d_out
    hipLaunchKernelGGL((gemm_g<3>), gu, blk, 0, stream, (const short*)O3t_h, (const short*)O3t_l,
                       (const float*)uw, (const float*)ub, (float*)d_out, CIN, COUT, det);
}